// Round 1
// baseline (29.810 us; speedup 1.0000x reference)
//
#include <hip/hip_runtime.h>

// LengthRegulator: B=32, T=512, D=384, max_len=2048 (fixed by setup_inputs).
// Outputs concatenated flat in d_out (float32): out[B][max_len][D], then mel_len[B] as float.

#define T_IN   512
#define D_DIM  384
#define D4     (D_DIM / 4)     // 96 float4 per row
#define MAXLEN 2048
#define B_SZ   32
#define ROWS_PER_BLOCK 16

// Kernel A: per-batch inclusive scan of duration -> cum (ws), mel_len -> d_out tail.
__global__ __launch_bounds__(T_IN) void lr_scan_kernel(const int* __restrict__ dur,
                                                       int* __restrict__ cum_ws,
                                                       float* __restrict__ mel_out) {
    __shared__ int s[T_IN];
    const int b = blockIdx.x;
    const int t = threadIdx.x;
    s[t] = dur[b * T_IN + t];
    __syncthreads();
    #pragma unroll
    for (int off = 1; off < T_IN; off <<= 1) {
        int v = s[t];
        int add = (t >= off) ? s[t - off] : 0;
        __syncthreads();
        s[t] = v + add;
        __syncthreads();
    }
    cum_ws[b * T_IN + t] = s[t];
    if (t == T_IN - 1) mel_out[b] = (float)s[t];
}

// Kernel B: binary-search gather + coalesced float4 expand.
__global__ __launch_bounds__(256) void lr_gather_kernel(const float* __restrict__ x,
                                                        const int* __restrict__ cum_ws,
                                                        float* __restrict__ out) {
    __shared__ int scum[T_IN];
    __shared__ int sidx[ROWS_PER_BLOCK];
    const int b = blockIdx.y;
    const int tid = threadIdx.x;

    // Stage cum[b][0..511] (2 KB) into LDS.
    const int* crow = cum_ws + b * T_IN;
    scum[tid] = crow[tid];
    scum[tid + 256] = crow[tid + 256];
    __syncthreads();

    // 16 binary searches: idx = first i with cum[i] > p  (searchsorted side='right').
    if (tid < ROWS_PER_BLOCK) {
        const int p = blockIdx.x * ROWS_PER_BLOCK + tid;
        const int mel = scum[T_IN - 1];
        int lo = 0, hi = T_IN;
        while (lo < hi) {
            int mid = (lo + hi) >> 1;
            if (scum[mid] <= p) lo = mid + 1; else hi = mid;
        }
        if (lo > T_IN - 1) lo = T_IN - 1;   // clip
        sidx[tid] = (p < mel) ? lo : -1;    // -1 => write zeros
    }
    __syncthreads();

    // Copy 16 rows x 96 float4 = 1536 float4, 6 per thread, fully coalesced stores.
    const float4* __restrict__ x4 = (const float4*)x;
    float4* __restrict__ out4 =
        (float4*)out + ((size_t)b * MAXLEN + (size_t)blockIdx.x * ROWS_PER_BLOCK) * D4;
    #pragma unroll
    for (int i = 0; i < 6; ++i) {
        int flat = i * 256 + tid;
        int row = flat / D4;            // constant divide -> magic multiply
        int chunk = flat - row * D4;
        int idx = sidx[row];
        float4 v = make_float4(0.f, 0.f, 0.f, 0.f);
        if (idx >= 0)
            v = x4[((size_t)b * T_IN + idx) * D4 + chunk];
        out4[flat] = v;
    }
}

extern "C" void kernel_launch(void* const* d_in, const int* in_sizes, int n_in,
                              void* d_out, int out_size, void* d_ws, size_t ws_size,
                              hipStream_t stream) {
    const float* x = (const float*)d_in[0];
    const int* dur = (const int*)d_in[1];
    // d_in[2] = max_len (2048), value fixed by setup; grid computed host-side.

    float* out = (float*)d_out;
    float* mel_out = out + (size_t)B_SZ * MAXLEN * D_DIM;  // tail: mel_len as float
    int* cum_ws = (int*)d_ws;                               // B*T ints = 64 KB

    lr_scan_kernel<<<B_SZ, T_IN, 0, stream>>>(dur, cum_ws, mel_out);

    dim3 grid(MAXLEN / ROWS_PER_BLOCK, B_SZ);  // (128, 32)
    lr_gather_kernel<<<grid, 256, 0, stream>>>(x, cum_ws, out);
}

// Round 3
// 24.653 us; speedup vs baseline: 1.2092x; 1.2092x over previous
//
#include <hip/hip_runtime.h>

// LengthRegulator: B=32, T=512, D=384, max_len=2048 (fixed by setup_inputs).
// Output flat in d_out (float32): out[B][max_len][D], then mel_len[B] as float.
// Single fused kernel: per-block redundant scan of duration (2 KB, L2-hot) ->
// binary-search idx for this block's 16 output rows -> coalesced float4 expand.

#define T_IN   512
#define D_DIM  384
#define D4     (D_DIM / 4)     // 96 float4 per row
#define MAXLEN 2048
#define B_SZ   32
#define ROWS_PER_BLOCK 16

typedef float f32x4 __attribute__((ext_vector_type(4)));  // native vector: OK for nontemporal builtins

__global__ __launch_bounds__(256) void lr_fused_kernel(const float* __restrict__ x,
                                                       const int* __restrict__ dur,
                                                       float* __restrict__ out,
                                                       float* __restrict__ mel_out) {
    __shared__ int scum[T_IN];
    __shared__ int sp[256];
    __shared__ int sidx[ROWS_PER_BLOCK];
    const int b = blockIdx.y;
    const int tid = threadIdx.x;

    // ---- Redundant per-block scan of duration[b][0..511] (pair-sum Hillis-Steele).
    int2 d2 = ((const int2*)(dur + b * T_IN))[tid];   // coalesced 8B/thread
    const int pair = d2.x + d2.y;
    sp[tid] = pair;
    __syncthreads();
    #pragma unroll
    for (int off = 1; off < 256; off <<= 1) {
        int v = sp[tid];
        int add = (tid >= off) ? sp[tid - off] : 0;
        __syncthreads();
        sp[tid] = v + add;
        __syncthreads();
    }
    const int excl = sp[tid] - pair;                  // exclusive pair-prefix
    scum[2 * tid]     = excl + d2.x;                  // 2-way bank alias: free
    scum[2 * tid + 1] = excl + d2.x + d2.y;
    __syncthreads();

    const int mel = scum[T_IN - 1];
    if (blockIdx.x == 0 && tid == 0) mel_out[b] = (float)mel;

    // ---- 16 binary searches: idx = first i with cum[i] > p (searchsorted 'right').
    if (tid < ROWS_PER_BLOCK) {
        const int p = blockIdx.x * ROWS_PER_BLOCK + tid;
        int lo = 0, hi = T_IN;
        while (lo < hi) {
            int mid = (lo + hi) >> 1;
            if (scum[mid] <= p) lo = mid + 1; else hi = mid;
        }
        if (lo > T_IN - 1) lo = T_IN - 1;             // clip
        sidx[tid] = (p < mel) ? lo : -1;              // -1 => zeros
    }
    __syncthreads();

    // ---- Copy 16 rows x 96 float4, 6 float4/thread, coalesced streaming stores.
    const f32x4* __restrict__ x4 = (const f32x4*)x;
    f32x4* __restrict__ out4 =
        (f32x4*)out + ((size_t)b * MAXLEN + (size_t)blockIdx.x * ROWS_PER_BLOCK) * D4;
    #pragma unroll
    for (int i = 0; i < 6; ++i) {
        int flat = i * 256 + tid;
        int row = flat / D4;            // constant divide -> magic multiply
        int chunk = flat - row * D4;
        int idx = sidx[row];
        f32x4 v = (f32x4)(0.f);
        if (idx >= 0)
            v = x4[((size_t)b * T_IN + idx) * D4 + chunk];
        __builtin_nontemporal_store(v, &out4[flat]);
    }
}

extern "C" void kernel_launch(void* const* d_in, const int* in_sizes, int n_in,
                              void* d_out, int out_size, void* d_ws, size_t ws_size,
                              hipStream_t stream) {
    const float* x = (const float*)d_in[0];
    const int* dur = (const int*)d_in[1];
    // d_in[2] = max_len (2048), fixed by setup; grid computed host-side.

    float* out = (float*)d_out;
    float* mel_out = out + (size_t)B_SZ * MAXLEN * D_DIM;  // tail: mel_len as float

    dim3 grid(MAXLEN / ROWS_PER_BLOCK, B_SZ);  // (128, 32)
    lr_fused_kernel<<<grid, 256, 0, stream>>>(x, dur, out, mel_out);
}